// Round 22
// baseline (325.100 us; speedup 1.0000x reference)
//
#include <hip/hip_runtime.h>
#include <hip/hip_bf16.h>

// B=32, Q=16, F=4096, E=256, NL=8, L=2 residual layers per mapper.
#define B_   32
#define Q_   16
#define F_   4096
#define E_   256
#define NL_  8
#define FT   64     // feature rows per block-chunk
#define NCH  64     // chunks per batch (NCH*FT == F_)
#define TPB  256    // 4 waves; wave owns 64 e-rows

typedef __attribute__((ext_vector_type(8))) __bf16 bf16x8_t;
typedef __attribute__((ext_vector_type(4))) __bf16 bf16x4_t;
typedef __attribute__((ext_vector_type(4))) float  f32x4;

// ---- LDS swizzle for [64][256] bf16 tiles (row stride 512 B) ----
__device__ __forceinline__ int swz(int r) {
  return ((r & 7) << 4) ^ (((r >> 3) & 3) << 5);
}
__device__ __forceinline__ int xoff(int r, int c2) {  // c2 = byte offset in row [0,512)
  return r * 512 + (c2 ^ swz(r));
}
__device__ __forceinline__ unsigned short f2bf_bits(float f) {
  __bf16 h = (__bf16)f;
  return __builtin_bit_cast(unsigned short, h);
}

// ---------------- prep: coalesced tiled transposes (8 mats, all bf16) -------
__global__ __launch_bounds__(256) void prep_kernel(
    const float* __restrict__ Wf, const float* __restrict__ Wv,
    const float* __restrict__ Wq, const float* __restrict__ Wc,
    unsigned short* __restrict__ WtF, unsigned short* __restrict__ WtV,
    unsigned short* __restrict__ WqT, unsigned short* __restrict__ WcT) {
  const int blk = blockIdx.x;
  const int t = threadIdx.x;
  __shared__ float ts[64][65];
  const int mat = blk >> 4;
  const int t16 = blk & 15;
  const int k0 = (t16 >> 2) * 64, n0 = (t16 & 3) * 64;
  const float* src;
  if (mat < 2) src = Wf + mat * 65536;
  else if (mat < 4) src = Wv + (mat - 2) * 65536;
  else if (mat < 6) src = Wq + (mat - 4) * 65536;
  else src = Wc + (mat - 6) * 65536;
#pragma unroll
  for (int p = 0; p < 16; ++p) {
    int e = p * 256 + t;
    int kk = e >> 6, nn = e & 63;
    ts[nn][kk] = src[(k0 + kk) * 256 + n0 + nn];   // coalesced in nn
  }
  __syncthreads();
  unsigned short* dst;
  if (mat < 2) dst = WtF + mat * 65536;
  else if (mat < 4) dst = WtV + (mat - 2) * 65536;
  else if (mat < 6) dst = WqT + (mat - 4) * 65536;
  else dst = WcT + (mat - 6) * 65536;
#pragma unroll
  for (int p = 0; p < 16; ++p) {
    int e = p * 256 + t;
    int nn = e >> 6, kk = e & 63;
    dst[(n0 + nn) * 256 + k0 + kk] = f2bf_bits(ts[nn][kk]);  // coalesced in kk
  }
}

// ---------------- staging: fp32 global -> bf16 swizzled LDS (256 thr) -------
__device__ __forceinline__ void stage_tile(char* Xs, const float* __restrict__ src, int tid) {
#pragma unroll
  for (int j = 0; j < 8; ++j) {
    int u = j * 256 + tid;                 // 2048 16B-units (64 rows)
    int r = u >> 5;
    const f32x4* p = (const f32x4*)(src + (size_t)r * E_ + ((u & 31) << 3));
    f32x4 a = __builtin_nontemporal_load(p);
    f32x4 b = __builtin_nontemporal_load(p + 1);
    bf16x8_t o;
    o[0] = (__bf16)a[0]; o[1] = (__bf16)a[1]; o[2] = (__bf16)a[2]; o[3] = (__bf16)a[3];
    o[4] = (__bf16)b[0]; o[5] = (__bf16)b[1]; o[6] = (__bf16)b[2]; o[7] = (__bf16)b[3];
    *(bf16x8_t*)(Xs + xoff(r, (u & 31) << 4)) = o;
  }
}

// ---- In-place residual layer over [64][256], 4 waves, wave owns 64 e-rows. -
// In-loop weight loads (compiler-scheduled). 2 barriers.
__device__ __forceinline__ void layer_ip(char* __restrict__ X,
                                         const unsigned short* __restrict__ Wt,
                                         const float* __restrict__ bias, int w, int lane) {
  const int c16 = lane & 15, g = lane >> 4, kb = g << 3;
  const unsigned short* wr0 = Wt + (w * 64 + c16) * E_ + kb;

  f32x4 acc[4][4];
#pragma unroll
  for (int ef = 0; ef < 4; ++ef)
#pragma unroll
    for (int mf = 0; mf < 4; ++mf) acc[ef][mf] = (f32x4){0.f, 0.f, 0.f, 0.f};

#pragma unroll
  for (int ks = 0; ks < 8; ++ks) {
    const int k = ks * 32 + kb;
    bf16x8_t wv[4];
#pragma unroll
    for (int ef = 0; ef < 4; ++ef)
      wv[ef] = *(const bf16x8_t*)(wr0 + ef * 16 * E_ + ks * 32);
#pragma unroll
    for (int mf = 0; mf < 4; ++mf) {
      bf16x8_t xb = *(const bf16x8_t*)(X + xoff(mf * 16 + c16, k << 1));
#pragma unroll
      for (int ef = 0; ef < 4; ++ef)
        acc[ef][mf] = __builtin_amdgcn_mfma_f32_16x16x32_bf16(wv[ef], xb, acc[ef][mf], 0, 0, 0);
    }
  }
  __syncthreads();   // all waves' reads of X done before in-place writes
#pragma unroll
  for (int ef = 0; ef < 4; ++ef) {
    const int e0 = w * 64 + ef * 16 + (g << 2);
    const float4 b4 = *(const float4*)(bias + e0);
#pragma unroll
    for (int mf = 0; mf < 4; ++mf) {
      const int m = mf * 16 + c16;
      bf16x4_t* p = (bf16x4_t*)(X + xoff(m, e0 << 1));
      bf16x4_t old = *p;
      bf16x4_t nw;
      nw[0] = (__bf16)(fmaxf(acc[ef][mf][0] + b4.x, 0.f) + (float)old[0]);
      nw[1] = (__bf16)(fmaxf(acc[ef][mf][1] + b4.y, 0.f) + (float)old[1]);
      nw[2] = (__bf16)(fmaxf(acc[ef][mf][2] + b4.z, 0.f) + (float)old[2]);
      nw[3] = (__bf16)(fmaxf(acc[ef][mf][3] + b4.w, 0.f) + (float)old[3]);
      *p = nw;
    }
  }
  __syncthreads();
}

// ---------------- q-mapper via MFMA: 512 rows = B*Q, 8 blocks ---------------
__global__ __launch_bounds__(TPB) void qmap_kernel(
    const float* __restrict__ query, const unsigned short* __restrict__ WqT,
    const float* __restrict__ bq, unsigned short* __restrict__ qmb) {
  const int blk = blockIdx.x;                 // rows [blk*64, blk*64+64)
  const int tid = threadIdx.x;
  const int lane = tid & 63, w = tid >> 6;

  __shared__ __align__(128) char X[32768];

  stage_tile(X, query + (size_t)blk * 64 * E_, tid);
  __syncthreads();

  layer_ip(X, WqT, bq, w, lane);
  layer_ip(X, WqT + 65536, bq + E_, w, lane);

#pragma unroll
  for (int j = 0; j < 8; ++j) {
    int u = j * 256 + tid;
    int r = u >> 5;
    bf16x8_t v = *(const bf16x8_t*)(X + xoff(r, (u & 31) << 4));
    *(bf16x8_t*)(qmb + (size_t)(blk * 64 + r) * E_ + ((u & 31) << 3)) = v;
  }
}

// ---------------- pass A: one 64-row chunk per block ------------------------
__global__ __launch_bounds__(TPB) void passA_kernel(
    const float* __restrict__ features,
    const float* __restrict__ amask, const float* __restrict__ ftw,
    const unsigned short* __restrict__ WtF, const float* __restrict__ bfb,
    const unsigned short* __restrict__ qmb, unsigned short* __restrict__ Wsg) {
  const int bid0 = blockIdx.x;
  const int bid = (bid0 & 7) * 256 + (bid0 >> 3);  // XCD swizzle (2048 = 8*256)
  const int b = bid >> 6, ch = bid & 63;
  const int tid = threadIdx.x;
  const int lane = tid & 63, w = tid >> 6;
  const int c16 = lane & 15, g = lane >> 4, kb = g << 3;
  const int f0 = ch * FT;

  __shared__ __align__(128) char X[32768];   // 32 KB -> 4 blocks/CU

  stage_tile(X, features + (size_t)(b * F_ + f0) * E_, tid);
  __syncthreads();

  layer_ip(X, WtF, bfb, w, lane);
  layer_ip(X, WtF + 65536, bfb + E_, w, lane);

  // ---- S = qm @ Fm^T (all 4 waves; wave w owns f rows [w*16, w*16+16)) ----
  {
    f32x4 sv = (f32x4){0.f, 0.f, 0.f, 0.f};
    const int fl = w * 16 + c16;
    const unsigned short* qbase = qmb + (size_t)(b * Q_ + c16) * E_ + kb;
#pragma unroll
    for (int ks = 0; ks < 8; ++ks) {
      bf16x8_t qa = *(const bf16x8_t*)(qbase + ks * 32);
      bf16x8_t xb = *(const bf16x8_t*)(X + xoff(fl, (ks * 32 + kb) << 1));
      sv = __builtin_amdgcn_mfma_f32_16x16x32_bf16(qa, xb, sv, 0, 0, 0);
    }
    const int fg = f0 + fl;
    const float lw = ftw[b * F_ + fg] * amask[b * F_ + fg];
#pragma unroll
    for (int r = 0; r < 4; ++r) {
      float sg = 1.f / (1.f + __expf(-sv[r]));
      Wsg[((size_t)(b * Q_ + g * 4 + r)) * F_ + fg] = f2bf_bits(sg * lw);
    }
  }
}

// ---------------- pass B: one 64-row chunk per block -> bf16 partial --------
__global__ __launch_bounds__(TPB) void passB_kernel(
    const float* __restrict__ values,
    const unsigned short* __restrict__ WtV, const float* __restrict__ bvb,
    const unsigned short* __restrict__ Wsg, unsigned short* __restrict__ partials) {
  const int bid0 = blockIdx.x;
  const int bid = (bid0 & 7) * 256 + (bid0 >> 3);
  const int b = bid >> 6, ch = bid & 63;
  const int tid = threadIdx.x;
  const int lane = tid & 63, w = tid >> 6;
  const int c16 = lane & 15, g = lane >> 4, kb = g << 3;
  const int f0 = ch * FT;

  __shared__ __align__(128) char X[32768];
  __shared__ __align__(16) unsigned short Wl[Q_][FT + 8];

  stage_tile(X, values + (size_t)(b * F_ + f0) * E_, tid);
  // attn weights for this chunk: 1024 = 16 q x 64 f, 4 per thread
#pragma unroll
  for (int kk = 0; kk < 4; ++kk) {
    int idx = tid + kk * 256;
    int q = idx >> 6, j = idx & 63;
    Wl[q][j] = Wsg[((size_t)(b * Q_ + q)) * F_ + f0 + j];
  }
  __syncthreads();

  layer_ip(X, WtV, bvb, w, lane);
  layer_ip(X, WtV + 65536, bvb + E_, w, lane);

  // ---- P = Wl[16,FT] @ Vm[FT,256]; wave w owns e in [w*64, w*64+64) ----
  f32x4 pacc[4];
#pragma unroll
  for (int nf = 0; nf < 4; ++nf) pacc[nf] = (f32x4){0.f, 0.f, 0.f, 0.f};
#pragma unroll
  for (int ks = 0; ks < FT / 32; ++ks) {
    bf16x8_t a = *(const bf16x8_t*)&Wl[c16][ks * 32 + kb];
#pragma unroll
    for (int nf = 0; nf < 4; ++nf) {
      const int e = w * 64 + nf * 16 + c16;
      bf16x8_t bb;
#pragma unroll
      for (int i = 0; i < 8; ++i) {
        const int f = ks * 32 + kb + i;
        bb[i] = *(const __bf16*)(X + xoff(f, e << 1));
      }
      pacc[nf] = __builtin_amdgcn_mfma_f32_16x16x32_bf16(a, bb, pacc[nf], 0, 0, 0);
    }
  }

  // ---- write bf16 partial [b][ch][q][e]; D[q][e]: q = g*4+r ----
#pragma unroll
  for (int nf = 0; nf < 4; ++nf) {
    const int e = w * 64 + nf * 16 + c16;
#pragma unroll
    for (int r = 0; r < 4; ++r) {
      const int q = g * 4 + r;
      partials[(((size_t)(b * NCH + ch)) * Q_ + q) * E_ + e] = f2bf_bits(pacc[nf][r]);
    }
  }
}

// ---------------- tail: reduce bf16 partials + c-mapper + out-proj ----------
__global__ __launch_bounds__(TPB) void tail_kernel(
    const unsigned short* __restrict__ partials, const unsigned short* __restrict__ WcT,
    const float* __restrict__ bc, const float* __restrict__ Wout,
    const float* __restrict__ bout, float* __restrict__ out) {
  const int blk = blockIdx.x;                 // rows [blk*64, blk*64+64) of B*Q
  const int tid = threadIdx.x;
  const int lane = tid & 63, w = tid >> 6;

  __shared__ __align__(128) char X[32768];

  // ---- reduce 64 bf16 partials -> bf16 swizzled tile ----
#pragma unroll
  for (int j = 0; j < 8; ++j) {
    int u = j * 256 + tid;
    int rl = u >> 5;
    int R = blk * 64 + rl;
    int b = R >> 4, q = R & 15;
    int e0 = (u & 31) << 3;
    float s[8];
#pragma unroll
    for (int i = 0; i < 8; ++i) s[i] = 0.f;
    for (int c = 0; c < NCH; ++c) {
      bf16x8_t pv = *(const bf16x8_t*)(partials + (((size_t)(b * NCH + c)) * Q_ + q) * E_ + e0);
#pragma unroll
      for (int i = 0; i < 8; ++i) s[i] += (float)pv[i];
    }
    bf16x8_t o;
#pragma unroll
    for (int i = 0; i < 8; ++i) o[i] = (__bf16)s[i];
    *(bf16x8_t*)(X + xoff(rl, e0 << 1)) = o;
  }
  __syncthreads();

  layer_ip(X, WcT, bc, w, lane);
  layer_ip(X, WcT + 65536, bc + E_, w, lane);

  // ---- out-proj: 512 (row,label) pairs over 256 threads ----
#pragma unroll
  for (int p = 0; p < 2; ++p) {
    const int idx = tid + p * 256;
    const int rl = idx >> 3, n = idx & 7;
    const int R = blk * 64 + rl;
    float sum = bout[n];
#pragma unroll
    for (int k0 = 0; k0 < E_; k0 += 8) {
      bf16x8_t h8 = *(const bf16x8_t*)(X + xoff(rl, k0 << 1));
#pragma unroll
      for (int i = 0; i < 8; ++i)
        sum += (float)h8[i] * Wout[(k0 + i) * NL_ + n];
    }
    out[R * NL_ + n] = sum;
  }
}

// ---------------- launch -----------------------------------------------------
extern "C" void kernel_launch(void* const* d_in, const int* in_sizes, int n_in,
                              void* d_out, int out_size, void* d_ws, size_t ws_size,
                              hipStream_t stream) {
  (void)in_sizes; (void)n_in; (void)out_size; (void)ws_size;
  const float* query    = (const float*)d_in[0];
  const float* features = (const float*)d_in[1];
  const float* values   = (const float*)d_in[2];
  const float* amask    = (const float*)d_in[3];
  const float* ftw      = (const float*)d_in[4];
  const float* Wq       = (const float*)d_in[5];
  const float* bq       = (const float*)d_in[6];
  const float* Wf       = (const float*)d_in[7];
  const float* bfb      = (const float*)d_in[8];
  const float* Wv       = (const float*)d_in[9];
  const float* bvb      = (const float*)d_in[10];
  const float* Wc       = (const float*)d_in[11];
  const float* bcb      = (const float*)d_in[12];
  const float* Wout     = (const float*)d_in[13];
  const float* bout     = (const float*)d_in[14];
  float* out = (float*)d_out;

  char* ws = (char*)d_ws;
  unsigned short* WtF = (unsigned short*)(ws);             // 256 KB
  unsigned short* WtV = (unsigned short*)(ws + 262144);    // 256 KB
  unsigned short* WqT = (unsigned short*)(ws + 524288);    // 256 KB
  unsigned short* WcT = (unsigned short*)(ws + 786432);    // 256 KB
  unsigned short* qmb = (unsigned short*)(ws + 1048576);   // 256 KB
  unsigned short* Wsg = (unsigned short*)(ws + 1310720);   // 4 MB
  unsigned short* partials = (unsigned short*)(ws + 5505024); // 16.8 MB bf16

  prep_kernel<<<128, 256, 0, stream>>>(Wf, Wv, Wq, Wc, WtF, WtV, WqT, WcT);
  qmap_kernel<<<(B_ * Q_) / 64, TPB, 0, stream>>>(query, WqT, bq, qmb);
  passA_kernel<<<B_ * NCH, TPB, 0, stream>>>(features, amask, ftw,
                                             WtF, bfb, qmb, Wsg);
  passB_kernel<<<B_ * NCH, TPB, 0, stream>>>(values, WtV, bvb, Wsg, partials);
  tail_kernel<<<(B_ * Q_) / 64, TPB, 0, stream>>>(partials, WcT, bcb, Wout, bout, out);
}

// Round 23
// 295.489 us; speedup vs baseline: 1.1002x; 1.1002x over previous
//
#include <hip/hip_runtime.h>
#include <hip/hip_bf16.h>

// B=32, Q=16, F=4096, E=256, NL=8, L=2 residual layers per mapper.
#define B_   32
#define Q_   16
#define F_   4096
#define E_   256
#define NL_  8
#define FT   64     // feature rows per block-chunk
#define NCH  64     // chunks per batch (NCH*FT == F_)
#define TPB  256    // 4 waves; wave owns 64 e-rows

typedef __attribute__((ext_vector_type(8))) __bf16 bf16x8_t;
typedef __attribute__((ext_vector_type(4))) __bf16 bf16x4_t;
typedef __attribute__((ext_vector_type(4))) float  f32x4;

// ---- LDS swizzle for [64][256] bf16 tiles (row stride 512 B) ----
__device__ __forceinline__ int swz(int r) {
  return ((r & 7) << 4) ^ (((r >> 3) & 3) << 5);
}
__device__ __forceinline__ int xoff(int r, int c2) {  // c2 = byte offset in row [0,512)
  return r * 512 + (c2 ^ swz(r));
}
__device__ __forceinline__ unsigned short f2bf_bits(float f) {
  __bf16 h = (__bf16)f;
  return __builtin_bit_cast(unsigned short, h);
}

// ---------------- prep: coalesced tiled transposes (8 mats, all bf16) -------
__global__ __launch_bounds__(256) void prep_kernel(
    const float* __restrict__ Wf, const float* __restrict__ Wv,
    const float* __restrict__ Wq, const float* __restrict__ Wc,
    unsigned short* __restrict__ WtF, unsigned short* __restrict__ WtV,
    unsigned short* __restrict__ WqT, unsigned short* __restrict__ WcT) {
  const int blk = blockIdx.x;
  const int t = threadIdx.x;
  __shared__ float ts[64][65];
  const int mat = blk >> 4;
  const int t16 = blk & 15;
  const int k0 = (t16 >> 2) * 64, n0 = (t16 & 3) * 64;
  const float* src;
  if (mat < 2) src = Wf + mat * 65536;
  else if (mat < 4) src = Wv + (mat - 2) * 65536;
  else if (mat < 6) src = Wq + (mat - 4) * 65536;
  else src = Wc + (mat - 6) * 65536;
#pragma unroll
  for (int p = 0; p < 16; ++p) {
    int e = p * 256 + t;
    int kk = e >> 6, nn = e & 63;
    ts[nn][kk] = src[(k0 + kk) * 256 + n0 + nn];   // coalesced in nn
  }
  __syncthreads();
  unsigned short* dst;
  if (mat < 2) dst = WtF + mat * 65536;
  else if (mat < 4) dst = WtV + (mat - 2) * 65536;
  else if (mat < 6) dst = WqT + (mat - 4) * 65536;
  else dst = WcT + (mat - 6) * 65536;
#pragma unroll
  for (int p = 0; p < 16; ++p) {
    int e = p * 256 + t;
    int nn = e >> 6, kk = e & 63;
    dst[(n0 + nn) * 256 + k0 + kk] = f2bf_bits(ts[nn][kk]);  // coalesced in kk
  }
}

// ---------------- staging: fp32 global -> bf16 swizzled LDS (256 thr) -------
__device__ __forceinline__ void stage_tile(char* Xs, const float* __restrict__ src, int tid) {
#pragma unroll
  for (int j = 0; j < 8; ++j) {
    int u = j * 256 + tid;                 // 2048 16B-units (64 rows)
    int r = u >> 5;
    const f32x4* p = (const f32x4*)(src + (size_t)r * E_ + ((u & 31) << 3));
    f32x4 a = __builtin_nontemporal_load(p);
    f32x4 b = __builtin_nontemporal_load(p + 1);
    bf16x8_t o;
    o[0] = (__bf16)a[0]; o[1] = (__bf16)a[1]; o[2] = (__bf16)a[2]; o[3] = (__bf16)a[3];
    o[4] = (__bf16)b[0]; o[5] = (__bf16)b[1]; o[6] = (__bf16)b[2]; o[7] = (__bf16)b[3];
    *(bf16x8_t*)(Xs + xoff(r, (u & 31) << 4)) = o;
  }
}

// ---- In-place residual layer over [64][256], 4 waves, wave owns 64 e-rows. -
// In-loop weight loads (proven VGPR=84, spill-free). 2 barriers.
__device__ __forceinline__ void layer_ip(char* __restrict__ X,
                                         const unsigned short* __restrict__ Wt,
                                         const float* __restrict__ bias, int w, int lane) {
  const int c16 = lane & 15, g = lane >> 4, kb = g << 3;
  const unsigned short* wr0 = Wt + (w * 64 + c16) * E_ + kb;

  f32x4 acc[4][4];
#pragma unroll
  for (int ef = 0; ef < 4; ++ef)
#pragma unroll
    for (int mf = 0; mf < 4; ++mf) acc[ef][mf] = (f32x4){0.f, 0.f, 0.f, 0.f};

#pragma unroll
  for (int ks = 0; ks < 8; ++ks) {
    const int k = ks * 32 + kb;
    bf16x8_t wv[4];
#pragma unroll
    for (int ef = 0; ef < 4; ++ef)
      wv[ef] = *(const bf16x8_t*)(wr0 + ef * 16 * E_ + ks * 32);
#pragma unroll
    for (int mf = 0; mf < 4; ++mf) {
      bf16x8_t xb = *(const bf16x8_t*)(X + xoff(mf * 16 + c16, k << 1));
#pragma unroll
      for (int ef = 0; ef < 4; ++ef)
        acc[ef][mf] = __builtin_amdgcn_mfma_f32_16x16x32_bf16(wv[ef], xb, acc[ef][mf], 0, 0, 0);
    }
  }
  __syncthreads();   // all waves' reads of X done before in-place writes
#pragma unroll
  for (int ef = 0; ef < 4; ++ef) {
    const int e0 = w * 64 + ef * 16 + (g << 2);
    const float4 b4 = *(const float4*)(bias + e0);
#pragma unroll
    for (int mf = 0; mf < 4; ++mf) {
      const int m = mf * 16 + c16;
      bf16x4_t* p = (bf16x4_t*)(X + xoff(m, e0 << 1));
      bf16x4_t old = *p;
      bf16x4_t nw;
      nw[0] = (__bf16)(fmaxf(acc[ef][mf][0] + b4.x, 0.f) + (float)old[0]);
      nw[1] = (__bf16)(fmaxf(acc[ef][mf][1] + b4.y, 0.f) + (float)old[1]);
      nw[2] = (__bf16)(fmaxf(acc[ef][mf][2] + b4.z, 0.f) + (float)old[2]);
      nw[3] = (__bf16)(fmaxf(acc[ef][mf][3] + b4.w, 0.f) + (float)old[3]);
      *p = nw;
    }
  }
  __syncthreads();
}

// ---------------- q-mapper via MFMA: 512 rows = B*Q, 8 blocks ---------------
__global__ __launch_bounds__(TPB) void qmap_kernel(
    const float* __restrict__ query, const unsigned short* __restrict__ WqT,
    const float* __restrict__ bq, unsigned short* __restrict__ qmb) {
  const int blk = blockIdx.x;                 // rows [blk*64, blk*64+64)
  const int tid = threadIdx.x;
  const int lane = tid & 63, w = tid >> 6;

  __shared__ __align__(128) char X[32768];

  stage_tile(X, query + (size_t)blk * 64 * E_, tid);
  __syncthreads();

  layer_ip(X, WqT, bq, w, lane);
  layer_ip(X, WqT + 65536, bq + E_, w, lane);

#pragma unroll
  for (int j = 0; j < 8; ++j) {
    int u = j * 256 + tid;
    int r = u >> 5;
    bf16x8_t v = *(const bf16x8_t*)(X + xoff(r, (u & 31) << 4));
    *(bf16x8_t*)(qmb + (size_t)(blk * 64 + r) * E_ + ((u & 31) << 3)) = v;
  }
}

// ---------------- fused: F->f-mapper->S->Wl ; V->v-mapper->PV -> partial ----
__global__ __launch_bounds__(TPB) void fused_kernel(
    const float* __restrict__ features, const float* __restrict__ values,
    const float* __restrict__ amask, const float* __restrict__ ftw,
    const unsigned short* __restrict__ WtF, const float* __restrict__ bfb,
    const unsigned short* __restrict__ WtV, const float* __restrict__ bvb,
    const unsigned short* __restrict__ qmb, unsigned short* __restrict__ partials) {
  const int bid0 = blockIdx.x;
  const int bid = (bid0 & 7) * 256 + (bid0 >> 3);  // XCD swizzle (2048 = 8*256)
  const int b = bid >> 6, ch = bid & 63;
  const int tid = threadIdx.x;
  const int lane = tid & 63, w = tid >> 6;
  const int c16 = lane & 15, g = lane >> 4, kb = g << 3;
  const int f0 = ch * FT;

  __shared__ __align__(128) char X[32768];                 // 32 KB tile
  __shared__ __align__(16) unsigned short Wl[Q_][FT + 8];  // attn weights

  // ---- features chunk -> f-mapper ----
  stage_tile(X, features + (size_t)(b * F_ + f0) * E_, tid);
  __syncthreads();

  layer_ip(X, WtF, bfb, w, lane);
  layer_ip(X, WtF + 65536, bfb + E_, w, lane);

  // ---- S = qm @ Fm^T (all 4 waves; wave w owns f rows [w*16, w*16+16)) ----
  {
    f32x4 sv = (f32x4){0.f, 0.f, 0.f, 0.f};
    const int fl = w * 16 + c16;
    const unsigned short* qbase = qmb + (size_t)(b * Q_ + c16) * E_ + kb;
#pragma unroll
    for (int ks = 0; ks < 8; ++ks) {
      bf16x8_t qa = *(const bf16x8_t*)(qbase + ks * 32);
      bf16x8_t xb = *(const bf16x8_t*)(X + xoff(fl, (ks * 32 + kb) << 1));
      sv = __builtin_amdgcn_mfma_f32_16x16x32_bf16(qa, xb, sv, 0, 0, 0);
    }
    const int fg = f0 + fl;
    const float lw = ftw[b * F_ + fg] * amask[b * F_ + fg];
#pragma unroll
    for (int r = 0; r < 4; ++r) {
      float sg = 1.f / (1.f + __expf(-sv[r]));
      Wl[g * 4 + r][fl] = f2bf_bits(sg * lw);
    }
  }
  __syncthreads();                      // S reads of X done; Wl complete

  // ---- values chunk -> v-mapper (reuse X) ----
  stage_tile(X, values + (size_t)(b * F_ + f0) * E_, tid);
  __syncthreads();

  layer_ip(X, WtV, bvb, w, lane);
  layer_ip(X, WtV + 65536, bvb + E_, w, lane);

  // ---- P = Wl[16,FT] @ Vm[FT,256]; wave w owns e in [w*64, w*64+64) ----
  f32x4 pacc[4];
#pragma unroll
  for (int nf = 0; nf < 4; ++nf) pacc[nf] = (f32x4){0.f, 0.f, 0.f, 0.f};
#pragma unroll
  for (int ks = 0; ks < FT / 32; ++ks) {
    bf16x8_t a = *(const bf16x8_t*)&Wl[c16][ks * 32 + kb];
#pragma unroll
    for (int nf = 0; nf < 4; ++nf) {
      const int e = w * 64 + nf * 16 + c16;
      bf16x8_t bb;
#pragma unroll
      for (int i = 0; i < 8; ++i) {
        const int f = ks * 32 + kb + i;
        bb[i] = *(const __bf16*)(X + xoff(f, e << 1));
      }
      pacc[nf] = __builtin_amdgcn_mfma_f32_16x16x32_bf16(a, bb, pacc[nf], 0, 0, 0);
    }
  }

  // ---- write bf16 partial [b][ch][q][e]; D[q][e]: q = g*4+r ----
#pragma unroll
  for (int nf = 0; nf < 4; ++nf) {
    const int e = w * 64 + nf * 16 + c16;
#pragma unroll
    for (int r = 0; r < 4; ++r) {
      const int q = g * 4 + r;
      partials[(((size_t)(b * NCH + ch)) * Q_ + q) * E_ + e] = f2bf_bits(pacc[nf][r]);
    }
  }
}

// ---------------- tail: reduce bf16 partials + c-mapper + out-proj ----------
__global__ __launch_bounds__(TPB) void tail_kernel(
    const unsigned short* __restrict__ partials, const unsigned short* __restrict__ WcT,
    const float* __restrict__ bc, const float* __restrict__ Wout,
    const float* __restrict__ bout, float* __restrict__ out) {
  const int blk = blockIdx.x;                 // rows [blk*64, blk*64+64) of B*Q
  const int tid = threadIdx.x;
  const int lane = tid & 63, w = tid >> 6;

  __shared__ __align__(128) char X[32768];

  // ---- reduce 64 bf16 partials -> bf16 swizzled tile ----
#pragma unroll
  for (int j = 0; j < 8; ++j) {
    int u = j * 256 + tid;
    int rl = u >> 5;
    int R = blk * 64 + rl;
    int b = R >> 4, q = R & 15;
    int e0 = (u & 31) << 3;
    float s[8];
#pragma unroll
    for (int i = 0; i < 8; ++i) s[i] = 0.f;
    for (int c = 0; c < NCH; ++c) {
      bf16x8_t pv = *(const bf16x8_t*)(partials + (((size_t)(b * NCH + c)) * Q_ + q) * E_ + e0);
#pragma unroll
      for (int i = 0; i < 8; ++i) s[i] += (float)pv[i];
    }
    bf16x8_t o;
#pragma unroll
    for (int i = 0; i < 8; ++i) o[i] = (__bf16)s[i];
    *(bf16x8_t*)(X + xoff(rl, e0 << 1)) = o;
  }
  __syncthreads();

  layer_ip(X, WcT, bc, w, lane);
  layer_ip(X, WcT + 65536, bc + E_, w, lane);

  // ---- out-proj: 512 (row,label) pairs over 256 threads ----
#pragma unroll
  for (int p = 0; p < 2; ++p) {
    const int idx = tid + p * 256;
    const int rl = idx >> 3, n = idx & 7;
    const int R = blk * 64 + rl;
    float sum = bout[n];
#pragma unroll
    for (int k0 = 0; k0 < E_; k0 += 8) {
      bf16x8_t h8 = *(const bf16x8_t*)(X + xoff(rl, k0 << 1));
#pragma unroll
      for (int i = 0; i < 8; ++i)
        sum += (float)h8[i] * Wout[(k0 + i) * NL_ + n];
    }
    out[R * NL_ + n] = sum;
  }
}

// ---------------- launch -----------------------------------------------------
extern "C" void kernel_launch(void* const* d_in, const int* in_sizes, int n_in,
                              void* d_out, int out_size, void* d_ws, size_t ws_size,
                              hipStream_t stream) {
  (void)in_sizes; (void)n_in; (void)out_size; (void)ws_size;
  const float* query    = (const float*)d_in[0];
  const float* features = (const float*)d_in[1];
  const float* values   = (const float*)d_in[2];
  const float* amask    = (const float*)d_in[3];
  const float* ftw      = (const float*)d_in[4];
  const float* Wq       = (const float*)d_in[5];
  const float* bq       = (const float*)d_in[6];
  const float* Wf       = (const float*)d_in[7];
  const float* bfb      = (const float*)d_in[8];
  const float* Wv       = (const float*)d_in[9];
  const float* bvb      = (const float*)d_in[10];
  const float* Wc       = (const float*)d_in[11];
  const float* bcb      = (const float*)d_in[12];
  const float* Wout     = (const float*)d_in[13];
  const float* bout     = (const float*)d_in[14];
  float* out = (float*)d_out;

  char* ws = (char*)d_ws;
  unsigned short* WtF = (unsigned short*)(ws);             // 256 KB
  unsigned short* WtV = (unsigned short*)(ws + 262144);    // 256 KB
  unsigned short* WqT = (unsigned short*)(ws + 524288);    // 256 KB
  unsigned short* WcT = (unsigned short*)(ws + 786432);    // 256 KB
  unsigned short* qmb = (unsigned short*)(ws + 1048576);   // 256 KB
  unsigned short* partials = (unsigned short*)(ws + 1310720); // 16.8 MB bf16

  prep_kernel<<<128, 256, 0, stream>>>(Wf, Wv, Wq, Wc, WtF, WtV, WqT, WcT);
  qmap_kernel<<<(B_ * Q_) / 64, TPB, 0, stream>>>(query, WqT, bq, qmb);
  fused_kernel<<<B_ * NCH, TPB, 0, stream>>>(features, values, amask, ftw,
                                             WtF, bfb, WtV, bvb, qmb, partials);
  tail_kernel<<<(B_ * Q_) / 64, TPB, 0, stream>>>(partials, WcT, bcb, Wout, bout, out);
}